// Round 11
// baseline (367.699 us; speedup 1.0000x reference)
//
#include <hip/hip_runtime.h>

#define NN 50000
#define NE 800000
#define CC 128
#define NL 3

typedef short bf16x8 __attribute__((ext_vector_type(8)));
typedef float f32x4 __attribute__((ext_vector_type(4)));
union U16 { uint4 u; bf16x8 v; };

__device__ __forceinline__ float b2f(unsigned short u) {
  return __uint_as_float(((unsigned int)u) << 16);
}
__device__ __forceinline__ unsigned short f2b(float f) {
  unsigned int x = __float_as_uint(f);
  x += 0x7fffu + ((x >> 16) & 1u);   // round-to-nearest-even
  return (unsigned short)(x >> 16);
}

// flags[0] = 1 if float tensors are bf16, 0 if f32.
// flags[1] = 1 if edge_index is int64 (odd 32-bit words all zero), 0 if int32.
__global__ void k_flags(const unsigned short* __restrict__ x,
                        const int* __restrict__ ei, int* __restrict__ flags) {
  __shared__ int cnt, any;
  if (threadIdx.x == 0) { cnt = 0; any = 0; }
  __syncthreads();
  if (threadIdx.x < 128) {
    unsigned short u = x[2 * threadIdx.x];
    int ex = (u >> 7) & 0xFF;
    if (ex >= 0x70 && ex <= 0x8F) atomicAdd(&cnt, 1);
  }
  if (ei[2 * threadIdx.x + 1] != 0) atomicOr(&any, 1);
  __syncthreads();
  if (threadIdx.x == 0) {
    flags[0] = (cnt >= 64) ? 1 : 0;
    flags[1] = (any == 0) ? 1 : 0;
  }
}

__device__ __forceinline__ int eidx(const int* ei, int row, int e, int f64) {
  return f64 ? ei[2 * ((size_t)row * NE + e)] : ei[(size_t)row * NE + e];
}

// ---- x -> bf16 workspace; no-op in bf16 mode (layer 0 reads d_in[0] direct) ----
__global__ __launch_bounds__(256) void k_cvt_x(const void* __restrict__ xin,
                                               unsigned short* __restrict__ xb,
                                               const int* __restrict__ flags) {
  if (flags[0]) return;
  int i = blockIdx.x * 256 + threadIdx.x;   // NN*CC/8 threads exactly
  const float4 a = ((const float4*)xin)[2 * i];
  const float4 b = ((const float4*)xin)[2 * i + 1];
  uint4 o;
  o.x = (unsigned)f2b(a.x) | ((unsigned)f2b(a.y) << 16);
  o.y = (unsigned)f2b(a.z) | ((unsigned)f2b(a.w) << 16);
  o.z = (unsigned)f2b(b.x) | ((unsigned)f2b(b.y) << 16);
  o.w = (unsigned)f2b(b.z) | ((unsigned)f2b(b.w) << 16);
  ((uint4*)xb)[i] = o;
}

// ---- params: W transpose->bf16 (wt[l][n][k]), bias/emlp -> f32 ----
__global__ __launch_bounds__(256) void k_cvt_par(const void* lw, const void* lb,
                                                 const void* emw, const void* emb,
                                                 unsigned short* __restrict__ wt,
                                                 float* lbf, float* emwf, float* embf,
                                                 const int* __restrict__ flags) {
  int i = blockIdx.x * 256 + threadIdx.x;
  const int bf = flags[0];
  if (i < NL * CC * CC) {
    unsigned short v = bf ? ((const unsigned short*)lw)[i]
                          : f2b(((const float*)lw)[i]);
    const int l = i >> 14, r = i & 16383, k = r >> 7, n = r & 127;
    wt[l * 16384 + n * 128 + k] = v;
  }
  if (i < NL * CC)
    lbf[i] = bf ? b2f(((const unsigned short*)lb)[i]) : ((const float*)lb)[i];
  if (i < NL * 8)
    emwf[i] = bf ? b2f(((const unsigned short*)emw)[i]) : ((const float*)emw)[i];
  if (i < NL)
    embf[i] = bf ? b2f(((const unsigned short*)emb)[i]) : ((const float*)emb)[i];
}

// ---- CSR build: histogram of dst ----
__global__ __launch_bounds__(256) void k_hist(const int* __restrict__ ei,
                                              int* __restrict__ deg,
                                              const int* __restrict__ flags) {
  int e = blockIdx.x * 256 + threadIdx.x;
  if (e >= NE) return;
  atomicAdd(&deg[eidx(ei, 1, e, flags[1])], 1);
}

// ---- 3-phase device-wide exclusive scan over deg[NN] ----
#define NI4 (NN / 4)
#define SCAN_BLKS ((NI4 + 255) / 256)   // 49
__global__ __launch_bounds__(256) void k_scan1(const int* __restrict__ deg,
                                               int* __restrict__ offs,
                                               int* __restrict__ bsum) {
  __shared__ int ls[256];
  const int t = threadIdx.x;
  const int g = blockIdx.x * 256 + t;
  int4 d = make_int4(0, 0, 0, 0);
  if (g < NI4) d = ((const int4*)deg)[g];
  const int s = d.x + d.y + d.z + d.w;
  ls[t] = s;
  __syncthreads();
#pragma unroll
  for (int off = 1; off < 256; off <<= 1) {
    int tmp = (t >= off) ? ls[t - off] : 0;
    __syncthreads();
    ls[t] += tmp;
    __syncthreads();
  }
  const int excl = ls[t] - s;
  if (g < NI4) {
    int4 o;
    o.x = excl; o.y = o.x + d.x; o.z = o.y + d.y; o.w = o.z + d.z;
    ((int4*)offs)[g] = o;
  }
  if (t == 255) bsum[blockIdx.x] = ls[255];
}

__global__ void k_scan2(const int* __restrict__ bsum, int* __restrict__ bbase,
                        int* __restrict__ offs) {
  if (threadIdx.x == 0) {
    int run = 0;
    for (int b = 0; b < SCAN_BLKS; ++b) { bbase[b] = run; run += bsum[b]; }
    offs[NN] = run;
  }
}

__global__ __launch_bounds__(256) void k_scan3(int* __restrict__ offs,
                                               int* __restrict__ cursor,
                                               const int* __restrict__ bbase) {
  const int g = blockIdx.x * 256 + threadIdx.x;
  if (g >= NI4) return;
  const int base = bbase[blockIdx.x];
  int4 o = ((int4*)offs)[g];
  o.x += base; o.y += base; o.z += base; o.w += base;
  ((int4*)offs)[g] = o;
  ((int4*)cursor)[g] = o;
}

// ---- CSR fill + all-layer edge weights, one scattered 8B store per edge:
//      esrt[pos] = {src | w0bf<<16, w1bf | w2bf<<16}, wl = softplus(ea.ew_l+eb_l)
__global__ __launch_bounds__(256) void k_fill2(const int* __restrict__ ei,
                                               const void* __restrict__ ea,
                                               const float* __restrict__ emwf,
                                               const float* __restrict__ embf,
                                               int* __restrict__ cursor,
                                               uint2* __restrict__ esrt,
                                               const int* __restrict__ flags) {
  int e = blockIdx.x * 256 + threadIdx.x;
  if (e >= NE) return;
  float a[8];
  if (flags[0]) {
    const uint4 v = ((const uint4*)ea)[e];
    unsigned int p[4] = {v.x, v.y, v.z, v.w};
#pragma unroll
    for (int q = 0; q < 4; ++q) {
      a[2 * q]     = __uint_as_float(p[q] << 16);
      a[2 * q + 1] = __uint_as_float(p[q] & 0xffff0000u);
    }
  } else {
    const float4 v0 = ((const float4*)ea)[2 * e];
    const float4 v1 = ((const float4*)ea)[2 * e + 1];
    a[0] = v0.x; a[1] = v0.y; a[2] = v0.z; a[3] = v0.w;
    a[4] = v1.x; a[5] = v1.y; a[6] = v1.z; a[7] = v1.w;
  }
  float w[NL];
#pragma unroll
  for (int l = 0; l < NL; ++l) {
    float z = embf[l];
#pragma unroll
    for (int k = 0; k < 8; ++k) z += a[k] * emwf[l * 8 + k];
    w[l] = (z > 20.f) ? z : log1pf(expf(z));
  }
  const int f64 = flags[1];
  const int d = eidx(ei, 1, e, f64);
  const int s = eidx(ei, 0, e, f64);
  const int pos = atomicAdd(&cursor[d], 1);
  esrt[pos] = make_uint2((unsigned)s | ((unsigned)f2b(w[0]) << 16),
                         (unsigned)f2b(w[1]) | ((unsigned)f2b(w[2]) << 16));
}

__device__ __forceinline__ float wsel(uint2 p, int layer) {
  const unsigned u = (layer == 0) ? (p.x & 0xffff0000u)
                   : (layer == 1) ? (p.y << 16) : (p.y & 0xffff0000u);
  return __uint_as_float(u);
}

// ---- gather (bf16): agg[n] = sum w*x[src] - (sum w)*x[n]; one wave/node.
// 16-edge straight-line unroll: 32 loads in flight per latency exposure.
__global__ __launch_bounds__(256) void k_gather(const int* __restrict__ offs,
                                                const uint2* __restrict__ esrt,
                                                const unsigned short* xb_,
                                                const unsigned short* alt,
                                                int sel, int layer,
                                                unsigned short* __restrict__ agg,
                                                const int* __restrict__ flags) {
  const unsigned short* xb = (sel && flags[0]) ? alt : xb_;
  const int node = blockIdx.x * 4 + (threadIdx.x >> 6);
  const int c = (threadIdx.x & 63) * 2;
  float ax = 0.f, ay = 0.f, sw = 0.f;
  int j = offs[node];
  const int j1 = offs[node + 1];
  for (; j + 16 <= j1; j += 16) {
    uint2 p[16];
    unsigned v[16];
#pragma unroll
    for (int q = 0; q < 16; ++q) p[q] = esrt[j + q];
#pragma unroll
    for (int q = 0; q < 16; ++q)
      v[q] = *(const unsigned*)&xb[(size_t)(p[q].x & 0xffffu) * CC + c];
#pragma unroll
    for (int q = 0; q < 16; ++q) {
      const float w = wsel(p[q], layer);
      ax += w * __uint_as_float(v[q] << 16);
      ay += w * __uint_as_float(v[q] & 0xffff0000u);
      sw += w;
    }
  }
  for (; j + 4 <= j1; j += 4) {
    uint2 p[4];
    unsigned v[4];
#pragma unroll
    for (int q = 0; q < 4; ++q) p[q] = esrt[j + q];
#pragma unroll
    for (int q = 0; q < 4; ++q)
      v[q] = *(const unsigned*)&xb[(size_t)(p[q].x & 0xffffu) * CC + c];
#pragma unroll
    for (int q = 0; q < 4; ++q) {
      const float w = wsel(p[q], layer);
      ax += w * __uint_as_float(v[q] << 16);
      ay += w * __uint_as_float(v[q] & 0xffff0000u);
      sw += w;
    }
  }
  for (; j < j1; ++j) {
    const uint2 p0 = esrt[j];
    const float w0 = wsel(p0, layer);
    const unsigned v0 = *(const unsigned*)&xb[(size_t)(p0.x & 0xffffu) * CC + c];
    ax += w0 * __uint_as_float(v0 << 16);
    ay += w0 * __uint_as_float(v0 & 0xffff0000u);
    sw += w0;
  }
  const unsigned xi = *(const unsigned*)&xb[(size_t)node * CC + c];
  const float rx = ax - sw * __uint_as_float(xi << 16);
  const float ry = ay - sw * __uint_as_float(xi & 0xffff0000u);
  *(unsigned*)&agg[(size_t)node * CC + c] =
      (unsigned)f2b(rx) | ((unsigned)f2b(ry) << 16);
}

// ---- MFMA gemm: y = agg @ W + b; relu+residual -> in-place agg, or final store.
#define LPAD 136
__global__ __launch_bounds__(256) void k_gemm(unsigned short* agg,
                                              const unsigned short* xc_,
                                              const unsigned short* alt,
                                              int sel,
                                              const unsigned short* __restrict__ wt,
                                              const float* __restrict__ lbf,
                                              int layer, void* outp, int last,
                                              const int* __restrict__ flags) {
  const unsigned short* xc = (sel && flags[0]) ? alt : xc_;
  __shared__ unsigned short shA[64 * LPAD];    // 17408 B
  __shared__ unsigned short shB[128 * LPAD];   // 34816 B
  const int rb = blockIdx.x * 64;
  const unsigned short* wtl = wt + (size_t)layer * CC * CC;

  for (int u = threadIdx.x; u < 1024; u += 256) {        // A: 64 rows x 16 uint4
    const int row = u >> 4, q = u & 15;
    uint4 v = make_uint4(0, 0, 0, 0);
    if (rb + row < NN) v = *(const uint4*)&agg[(size_t)(rb + row) * CC + q * 8];
    *(uint4*)&shA[row * LPAD + q * 8] = v;
  }
  for (int u = threadIdx.x; u < 2048; u += 256) {        // B: 128 rows x 16 uint4
    const int row = u >> 4, q = u & 15;
    *(uint4*)&shB[row * LPAD + q * 8] = *(const uint4*)&wtl[row * 128 + q * 8];
  }
  __syncthreads();

  const int w = threadIdx.x >> 6;
  const int l = threadIdx.x & 63;
  const int lr = l & 15;
  const int lk = (l >> 4) * 8;

  U16 afr[4];
#pragma unroll
  for (int kk = 0; kk < 4; ++kk)
    afr[kk].u = *(const uint4*)&shA[(w * 16 + lr) * LPAD + kk * 32 + lk];

  const float* lbp = lbf + layer * CC;
  f32x4 acc[8];
#pragma unroll
  for (int t = 0; t < 8; ++t) {
    acc[t] = (f32x4){0.f, 0.f, 0.f, 0.f};
#pragma unroll
    for (int kk = 0; kk < 4; ++kk) {
      U16 bfr;
      bfr.u = *(const uint4*)&shB[(t * 16 + lr) * LPAD + kk * 32 + lk];
      acc[t] = __builtin_amdgcn_mfma_f32_16x16x32_bf16(afr[kk].v, bfr.v, acc[t], 0, 0, 0);
    }
  }

#pragma unroll
  for (int t = 0; t < 8; ++t) {
    const float bv = lbp[t * 16 + lr];
#pragma unroll
    for (int r = 0; r < 4; ++r) {
      const int tr = (l >> 4) * 4 + r;   // C/D: row = quad*4 + reg
      shA[(w * 16 + tr) * LPAD + t * 16 + lr] = f2b(acc[t][r] + bv);
    }
  }
  const int isbf = flags[0];
#pragma unroll
  for (int i = 0; i < 8; ++i) {
    const int idx = i * 64 + l;
    const int row = idx >> 5, cg = idx & 31;
    const int gr = rb + w * 16 + row;
    if (gr >= NN) continue;
    const uint2 yv = *(const uint2*)&shA[(w * 16 + row) * LPAD + cg * 4];
    float y0 = __uint_as_float(yv.x << 16);
    float y1 = __uint_as_float(yv.x & 0xffff0000u);
    float y2 = __uint_as_float(yv.y << 16);
    float y3 = __uint_as_float(yv.y & 0xffff0000u);
    const size_t off = (size_t)gr * CC + cg * 4;
    if (!last) {
      const uint2 rv = *(const uint2*)&xc[off];
      y0 = fmaxf(y0, 0.f) + __uint_as_float(rv.x << 16);
      y1 = fmaxf(y1, 0.f) + __uint_as_float(rv.x & 0xffff0000u);
      y2 = fmaxf(y2, 0.f) + __uint_as_float(rv.y << 16);
      y3 = fmaxf(y3, 0.f) + __uint_as_float(rv.y & 0xffff0000u);
      *(uint2*)&agg[off] = make_uint2((unsigned)f2b(y0) | ((unsigned)f2b(y1) << 16),
                                      (unsigned)f2b(y2) | ((unsigned)f2b(y3) << 16));
    } else if (isbf) {
      *(uint2*)&((unsigned short*)outp)[off] = yv;
    } else {
      *(float4*)&((float*)outp)[off] = make_float4(y0, y1, y2, y3);
    }
  }
}

extern "C" void kernel_launch(void* const* d_in, const int* in_sizes, int n_in,
                              void* d_out, int out_size, void* d_ws, size_t ws_size,
                              hipStream_t stream) {
  const unsigned short* x0 = (const unsigned short*)d_in[0];
  const int* ei = (const int*)d_in[1];

  const size_t nbuf = (size_t)NN * CC;
  unsigned short* xb0 = (unsigned short*)d_ws;
  unsigned short* xb1 = xb0 + nbuf;
  unsigned short* wt = xb1 + nbuf;
  uint2* esrt = (uint2*)(wt + (size_t)NL * CC * CC);
  int* deg = (int*)(esrt + NE);
  int* offs = deg + NN;
  int* cursor = offs + NN + 4;
  int* bsum = cursor + NN;
  int* bbase = bsum + 64;
  float* lbf = (float*)(bbase + 64);
  float* emwf = lbf + (size_t)NL * CC;
  float* embf = emwf + NL * 8;
  int* flags = (int*)(embf + NL);
  const size_t need = (size_t)((char*)(flags + 2) - (char*)d_ws);
  if (ws_size < need) {
    hipMemsetAsync(d_out, 0, (size_t)out_size * 2, stream);
    return;
  }

  k_flags<<<1, 256, 0, stream>>>(x0, ei, flags);
  k_cvt_x<<<(NN * CC / 8) / 256, 256, 0, stream>>>(d_in[0], xb0, flags);
  k_cvt_par<<<(NL * CC * CC + 255) / 256, 256, 0, stream>>>(
      d_in[3], d_in[4], d_in[5], d_in[6], wt, lbf, emwf, embf, flags);

  hipMemsetAsync(deg, 0, NN * sizeof(int), stream);
  k_hist<<<(NE + 255) / 256, 256, 0, stream>>>(ei, deg, flags);
  k_scan1<<<SCAN_BLKS, 256, 0, stream>>>(deg, offs, bsum);
  k_scan2<<<1, 64, 0, stream>>>(bsum, bbase, offs);
  k_scan3<<<SCAN_BLKS, 256, 0, stream>>>(offs, cursor, bbase);
  k_fill2<<<(NE + 255) / 256, 256, 0, stream>>>(ei, d_in[2], emwf, embf,
                                                cursor, esrt, flags);

  unsigned short* xc = xb0;
  unsigned short* ag = xb1;
  for (int layer = 0; layer < NL; ++layer) {
    const int sel = (layer == 0) ? 1 : 0;
    k_gather<<<NN / 4, 256, 0, stream>>>(offs, esrt, xc, x0, sel, layer, ag, flags);
    k_gemm<<<(NN + 63) / 64, 256, 0, stream>>>(ag, xc, x0, sel, wt, lbf, layer,
                                               d_out, layer == NL - 1 ? 1 : 0, flags);
    unsigned short* t = xc; xc = ag; ag = t;   // gemm wrote new x into ag
  }
}